// Round 4
// baseline (1108.829 us; speedup 1.0000x reference)
//
#include <hip/hip_runtime.h>
#include <hip/hip_fp16.h>

// MoE: B=4 S=2048 D=1024 E=8 K=2 H=4096. T=8192 tokens, 16384 assignments.
// R4: locality-ordered grids. FFN1 = 256 persistent blocks (one per (e,nt)
// B-panel, internal mt loop). FFN2 = XCD-pair swizzle (all mt of one (e,nt)
// panel on one XCD). 8-phase 256x256/BK=64 schedule unchanged (proven R3).

#define T_TOK 8192
#define D_IN  1024
#define E_EXP 8
#define H_HID 4096
#define NSLOT (T_TOK * 2)
#define NSLOT_PAD (NSLOT + 256)

typedef _Float16 f16;
typedef __attribute__((ext_vector_type(8))) _Float16 f16x8;
typedef __attribute__((ext_vector_type(4))) _Float16 f16x4;
typedef __attribute__((ext_vector_type(4))) float f32x4;

__device__ __forceinline__ void gload_lds16(const void* g, void* l) {
  __builtin_amdgcn_global_load_lds(
      (const __attribute__((address_space(1))) unsigned int*)g,
      (__attribute__((address_space(3))) unsigned int*)l, 16, 0, 0);
}

// ---------------- conversion kernels ----------------

__global__ __launch_bounds__(256) void convert_x_kernel(
    const float* __restrict__ x, f16* __restrict__ xb, int n4) {
  int i = blockIdx.x * 256 + threadIdx.x;
  if (i >= n4) return;
  float4 v = ((const float4*)x)[i];
  f16x4 o = {(f16)v.x, (f16)v.y, (f16)v.z, (f16)v.w};
  *(f16x4*)(xb + (size_t)i * 4) = o;
}

// src [e][R][C] f32 -> dst f16 [e][*][R]; MAP0: row=c; MAP1: gate interleave;
// MAP2: up interleave (rows 32j+16.. for source col 16j..).
template<int MAP>
__global__ __launch_bounds__(256) void transpose_cvt_kernel(
    const float* __restrict__ src, f16* __restrict__ dst, int R, int C,
    size_t dstride) {
  __shared__ float tile[32][33];
  int b = blockIdx.z;
  const float* s = src + (size_t)b * R * C;
  f16* d = dst + (size_t)b * dstride;
  int c0 = blockIdx.x * 32, r0 = blockIdx.y * 32;
  int tr = threadIdx.x >> 3;
  int tc4 = (threadIdx.x & 7) * 4;
  float4 v = *(const float4*)(s + (size_t)(r0 + tr) * C + c0 + tc4);
  tile[tr][tc4 + 0] = v.x;
  tile[tr][tc4 + 1] = v.y;
  tile[tr][tc4 + 2] = v.z;
  tile[tr][tc4 + 3] = v.w;
  __syncthreads();
  int c = c0 + tr;
  int ro = (MAP == 0) ? c : (((c >> 4) << 5) + ((MAP == 2) ? 16 : 0) + (c & 15));
  f16x4 o = {(f16)tile[tc4 + 0][tr], (f16)tile[tc4 + 1][tr],
             (f16)tile[tc4 + 2][tr], (f16)tile[tc4 + 3][tr]};
  *(f16x4*)(d + (size_t)ro * R + r0 + tc4) = o;
}

// ---------------- router ----------------

__global__ __launch_bounds__(256) void router_kernel(
    const float* __restrict__ x, const float* __restrict__ Wr,
    const float* __restrict__ br, int* __restrict__ eidx,
    float2* __restrict__ pval, int* __restrict__ counts) {
  int lane = threadIdx.x & 63, wid = threadIdx.x >> 6;
  int t = blockIdx.x * 4 + wid;
  const float* xr = x + (size_t)t * D_IN;
  float s[8] = {0.f, 0.f, 0.f, 0.f, 0.f, 0.f, 0.f, 0.f};
  int dbase = lane * 16;
#pragma unroll
  for (int i = 0; i < 4; ++i) {
    float4 xv = *(const float4*)(xr + dbase + i * 4);
    const float xs[4] = {xv.x, xv.y, xv.z, xv.w};
#pragma unroll
    for (int j = 0; j < 4; ++j) {
      const float* wr = Wr + (size_t)(dbase + i * 4 + j) * E_EXP;
      float4 w0 = *(const float4*)wr;
      float4 w1 = *(const float4*)(wr + 4);
      float xvj = xs[j];
      s[0] += xvj * w0.x; s[1] += xvj * w0.y; s[2] += xvj * w0.z; s[3] += xvj * w0.w;
      s[4] += xvj * w1.x; s[5] += xvj * w1.y; s[6] += xvj * w1.z; s[7] += xvj * w1.w;
    }
  }
#pragma unroll
  for (int off = 32; off; off >>= 1)
#pragma unroll
    for (int e = 0; e < 8; ++e) s[e] += __shfl_xor(s[e], off);
  if (lane == 0) {
    float v[8];
#pragma unroll
    for (int e = 0; e < 8; ++e) v[e] = s[e] + br[e];
    int i0 = 0; float v0 = v[0];
#pragma unroll
    for (int e = 1; e < 8; ++e) if (v[e] > v0) { v0 = v[e]; i0 = e; }
    int i1 = -1; float v1 = -1e30f;
#pragma unroll
    for (int e = 0; e < 8; ++e)
      if (e != i0 && v[e] > v1) { v1 = v[e]; i1 = e; }
    float ed = __expf(v1 - v0);
    float inv = 1.f / (1.f + ed);
    eidx[t] = i0 | (i1 << 8);
    pval[t] = make_float2(inv, ed * inv);
    atomicAdd(&counts[i0], 1);
    atomicAdd(&counts[i1], 1);
  }
}

__global__ void scan_kernel(const int* __restrict__ counts, int* __restrict__ offsets) {
  if (threadIdx.x == 0) {
    int acc = 0;
#pragma unroll
    for (int e = 0; e < E_EXP; ++e) { offsets[e] = acc; acc += counts[e]; }
    offsets[E_EXP] = acc;
  }
}

__global__ __launch_bounds__(256) void scatter_kernel(
    const int* __restrict__ eidx, const float2* __restrict__ pval,
    const int* __restrict__ offsets, int* __restrict__ cursors,
    int* __restrict__ perm, float* __restrict__ gatew, int2* __restrict__ slotAB) {
  int t = blockIdx.x * 256 + threadIdx.x;
  if (t >= T_TOK) return;
  int ei = eidx[t];
  float2 p = pval[t];
  int e0 = ei & 0xff, e1 = (ei >> 8) & 0xff;
  int s0 = offsets[e0] + atomicAdd(&cursors[e0], 1);
  perm[s0] = t; gatew[s0] = p.x;
  int s1 = offsets[e1] + atomicAdd(&cursors[e1], 1);
  perm[s1] = t; gatew[s1] = p.y;
  slotAB[t] = make_int2(s0, s1);
}

// ---------------- 8-phase 256x256 grouped GEMM ----------------
// 512 thr = 8 waves (2M x 4N). LDS 128KB: buf{0,1} x (A[256][64] | B[256][64]),
// rows 128B, 16B chunk c of row r at physical c^(r&7).
// MODE0 (FFN1): grid=256, block=(e,nt) persistent over mt. A=xb via perm,
//   B=wgut (gate/up 16-col interleave), K=1024, epilogue silu(g)*u -> hbuf.
// MODE1 (FFN2): grid=1024, XCD-pair swizzle. A=hbuf, B=wdt, K=4096,
//   epilogue gate*(acc+bd) -> ybuf.

#define SB0 __builtin_amdgcn_sched_barrier(0)
#define BAR do { SB0; __builtin_amdgcn_s_barrier(); SB0; } while (0)

#define STAGE_(B, ISB, H, KT, BASE) do {                                   \
  char* d_ = smem + (B)*65536 + (ISB)*32768 + (H)*16384 + wid*1024;        \
  gload_lds16(BASE[(H)*2+0] + (size_t)(KT)*64, d_);                        \
  gload_lds16(BASE[(H)*2+1] + (size_t)(KT)*64, d_ + 8192);                 \
} while (0)

#define LDA_(B, Q)                                                          \
  _Pragma("unroll")                                                         \
  for (int m_ = 0; m_ < 4; ++m_) {                                          \
    fa[m_][0] = *(const f16x8*)(smem + (B)*65536 + aoff + ((Q)*4+m_)*2048 + offk0); \
    fa[m_][1] = *(const f16x8*)(smem + (B)*65536 + aoff + ((Q)*4+m_)*2048 + offk1); \
  }

#define LDB_(FB, B, RH)                                                     \
  _Pragma("unroll")                                                         \
  for (int n_ = 0; n_ < 2; ++n_) {                                          \
    FB[n_][0] = *(const f16x8*)(smem + (B)*65536 + 32768 + boff + ((RH)*2+n_)*2048 + offk0); \
    FB[n_][1] = *(const f16x8*)(smem + (B)*65536 + 32768 + boff + ((RH)*2+n_)*2048 + offk1); \
  }

#define QUAD_(Q, RH, FB)                                                    \
  __builtin_amdgcn_s_setprio(1);                                            \
  _Pragma("unroll")                                                         \
  for (int m_ = 0; m_ < 4; ++m_)                                            \
    _Pragma("unroll")                                                       \
    for (int n_ = 0; n_ < 2; ++n_) {                                        \
      acc[(Q)*4+m_][(RH)*2+n_] = __builtin_amdgcn_mfma_f32_16x16x32_f16(    \
          fa[m_][0], FB[n_][0], acc[(Q)*4+m_][(RH)*2+n_], 0, 0, 0);         \
      acc[(Q)*4+m_][(RH)*2+n_] = __builtin_amdgcn_mfma_f32_16x16x32_f16(    \
          fa[m_][1], FB[n_][1], acc[(Q)*4+m_][(RH)*2+n_], 0, 0, 0);         \
    }                                                                       \
  __builtin_amdgcn_s_setprio(0);

template<int MODE>
__global__ __launch_bounds__(512, 2) void ffn_8ph_kernel(
    const f16* __restrict__ Asrc, const f16* __restrict__ Bsrc,
    const float* __restrict__ bias0, const float* __restrict__ bias1,
    const int* __restrict__ offsets, const int* __restrict__ perm,
    const float* __restrict__ gatew, f16* __restrict__ dst) {
  constexpr int KD = MODE ? H_HID : D_IN;        // K dim
  constexpr int BROWS = MODE ? D_IN : 2 * H_HID; // B rows per expert
  constexpr int NT = KD / 64;                    // K-tiles (even)
  static_assert(NT % 2 == 0, "NT even");

  __shared__ __align__(16) char smem[131072];

  int e, nt, mt0, mt1;
  int g = blockIdx.x;
  if constexpr (MODE == 0) {
    e = g >> 5; nt = g & 31;
  } else {
    int xcd = g & 7, r = g >> 3;
    int pair = xcd + 8 * (r & 3);   // all mt of one (e,nt) land on one XCD
    e = pair >> 2; nt = pair & 3; mt0 = r >> 2;
  }
  int off = offsets[e];
  int cnt = offsets[e + 1] - off;
  int ntiles = (cnt + 255) >> 8;
  if constexpr (MODE == 0) { mt0 = 0; mt1 = ntiles; }
  else { if (mt0 >= ntiles) return; mt1 = mt0 + 1; }

  int tid = threadIdx.x, lane = tid & 63, wid = tid >> 6;
  int wm = wid >> 2, wn = wid & 3;
  int l15 = lane & 15, lc0 = lane >> 4, s7 = l15 & 7;
  int aoff = (wm * 128 + l15) * 128;
  int boff = (wn * 64 + l15) * 128;
  int offk0 = ((lc0) ^ s7) * 16;
  int offk1 = ((lc0 + 4) ^ s7) * 16;

  // chunk geometry shared by A/B staging pointers
  int rowh_[2], lc_[2];
#pragma unroll
  for (int i = 0; i < 2; ++i) {
    int chunk = (i * 8 + wid) * 64 + lane;
    rowh_[i] = chunk >> 3;
    lc_[i] = (chunk & 7) ^ (rowh_[i] & 7);
  }

  // B stage pointers: mt-invariant
  const f16* bB[4];
#pragma unroll
  for (int h = 0; h < 2; ++h)
#pragma unroll
    for (int i = 0; i < 2; ++i)
      bB[h * 2 + i] =
          Bsrc + ((size_t)e * BROWS + nt * 256 + h * 128 + rowh_[i]) * KD + lc_[i] * 8;

  // hoisted biases
  float bv0[4], bv1[2];
  if constexpr (MODE == 0) {
#pragma unroll
    for (int p = 0; p < 2; ++p) {
      int h = nt * 128 + wn * 32 + p * 16 + l15;
      bv0[p] = bias0[e * H_HID + h];
      bv1[p] = bias1[e * H_HID + h];
    }
  } else {
#pragma unroll
    for (int n = 0; n < 4; ++n)
      bv0[n] = bias0[e * D_IN + nt * 256 + wn * 64 + n * 16 + l15];
  }

  for (int mt = mt0; mt < mt1; ++mt) {
    // A stage pointers for this tile
    const f16* aB[4];
#pragma unroll
    for (int h = 0; h < 2; ++h)
#pragma unroll
      for (int i = 0; i < 2; ++i) {
        int absrow = h * 128 + rowh_[i];
        int slot = off + min(mt * 256 + absrow, cnt - 1);
        if constexpr (MODE == 0)
          aB[h * 2 + i] = Asrc + (size_t)perm[slot] * KD + lc_[i] * 8;
        else
          aB[h * 2 + i] = Asrc + (size_t)slot * KD + lc_[i] * 8;
      }

    f32x4 acc[8][4] = {};
    f16x8 fa[4][2], fb01[2][2], fb23[2][2];

    // prologue: buf0 <- tile0 (B,A), buf1.B <- tile1
    // (prior iteration's epilogue stores were issued before these loads;
    //  vmcnt retires in order, so vmcnt(4) also drains them)
    STAGE_(0, 1, 0, 0, bB); STAGE_(0, 1, 1, 0, bB);
    STAGE_(0, 0, 0, 0, aB); STAGE_(0, 0, 1, 0, aB);
    STAGE_(1, 1, 0, 1, bB); STAGE_(1, 1, 1, 1, bB);
    asm volatile("s_waitcnt vmcnt(4)" ::: "memory");
    BAR;

    for (int it = 0; it < NT / 2; ++it) {
      int t1 = 2 * it + 1;
      int t2 = min(2 * it + 2, NT - 1);
      int t3 = min(2 * it + 3, NT - 1);
      // P1: compute t0.quad(0,0) from buf0; stage buf1.A0 (t1)
      LDA_(0, 0); LDB_(fb01, 0, 0); STAGE_(1, 0, 0, t1, aB);
      BAR; QUAD_(0, 0, fb01); BAR;
      // P2
      LDB_(fb23, 0, 1); STAGE_(1, 0, 1, t1, aB);
      BAR; QUAD_(0, 1, fb23); BAR;
      // P3
      LDA_(0, 1); STAGE_(0, 1, 0, t2, bB);
      BAR; QUAD_(1, 0, fb01); BAR;
      // P4
      STAGE_(0, 1, 1, t2, bB);
      asm volatile("s_waitcnt vmcnt(4)" ::: "memory");
      BAR; QUAD_(1, 1, fb23); BAR;
      // P5: compute t1 from buf1; stage buf0.A0 (t2)
      LDA_(1, 0); LDB_(fb01, 1, 0); STAGE_(0, 0, 0, t2, aB);
      BAR; QUAD_(0, 0, fb01); BAR;
      // P6
      LDB_(fb23, 1, 1); STAGE_(0, 0, 1, t2, aB);
      BAR; QUAD_(0, 1, fb23); BAR;
      // P7
      LDA_(1, 1); STAGE_(1, 1, 0, t3, bB);
      BAR; QUAD_(1, 0, fb01); BAR;
      // P8
      STAGE_(1, 1, 1, t3, bB);
      asm volatile("s_waitcnt vmcnt(4)" ::: "memory");
      BAR; QUAD_(1, 1, fb23); BAR;
    }

    asm volatile("s_waitcnt vmcnt(0)" ::: "memory");
    BAR;

    int c0_ = lc0 * 4;
    if constexpr (MODE == 0) {
#pragma unroll
      for (int p = 0; p < 2; ++p) {
        int h = nt * 128 + wn * 32 + p * 16 + l15;
#pragma unroll
        for (int m = 0; m < 8; ++m) {
          int lbase = mt * 256 + wm * 128 + m * 16 + c0_;
#pragma unroll
          for (int r = 0; r < 4; ++r) {
            if (lbase + r < cnt) {
              float gv = acc[m][2 * p][r] + bv0[p];
              float uv = acc[m][2 * p + 1][r] + bv1[p];
              dst[(size_t)(off + lbase + r) * H_HID + h] =
                  (f16)((gv / (1.f + __expf(-gv))) * uv);
            }
          }
        }
      }
    } else {
#pragma unroll
      for (int n = 0; n < 4; ++n) {
        int col = nt * 256 + wn * 64 + n * 16 + l15;
#pragma unroll
        for (int m = 0; m < 8; ++m) {
          int lbase = mt * 256 + wm * 128 + m * 16 + c0_;
#pragma unroll
          for (int r = 0; r < 4; ++r) {
            if (lbase + r < cnt) {
              int slot = off + lbase + r;
              dst[(size_t)slot * D_IN + col] =
                  (f16)(gatew[slot] * (acc[m][n][r] + bv0[n]));
            }
          }
        }
      }
    }
  }
}

// ---------------- combine: out[t] = ybuf[s0] + ybuf[s1] ----------------
__global__ __launch_bounds__(256) void combine_kernel(
    const f16* __restrict__ ybuf, const int2* __restrict__ slotAB,
    float* __restrict__ out) {
  int i = blockIdx.x * 256 + threadIdx.x;
  int t = i >> 7;
  int c8 = i & 127;
  int2 s = slotAB[t];
  f16x8 y0 = *(const f16x8*)(ybuf + (size_t)s.x * D_IN + c8 * 8);
  f16x8 y1 = *(const f16x8*)(ybuf + (size_t)s.y * D_IN + c8 * 8);
  float* o = out + (size_t)t * D_IN + c8 * 8;
  float4 o0 = make_float4((float)y0[0] + (float)y1[0], (float)y0[1] + (float)y1[1],
                          (float)y0[2] + (float)y1[2], (float)y0[3] + (float)y1[3]);
  float4 o1 = make_float4((float)y0[4] + (float)y1[4], (float)y0[5] + (float)y1[5],
                          (float)y0[6] + (float)y1[6], (float)y0[7] + (float)y1[7]);
  ((float4*)o)[0] = o0;
  ((float4*)o)[1] = o1;
}

// ---------------- launch ----------------

extern "C" void kernel_launch(void* const* d_in, const int* in_sizes, int n_in,
                              void* d_out, int out_size, void* d_ws, size_t ws_size,
                              hipStream_t stream) {
  const float* x  = (const float*)d_in[0];
  const float* Wr = (const float*)d_in[1];
  const float* br = (const float*)d_in[2];
  const float* Wg = (const float*)d_in[3];
  const float* bg = (const float*)d_in[4];
  const float* Wu = (const float*)d_in[5];
  const float* bu = (const float*)d_in[6];
  const float* Wd = (const float*)d_in[7];
  const float* bd = (const float*)d_in[8];
  float* out = (float*)d_out;

  char* ws = (char*)d_ws;
  size_t o = 0;
  auto alloc = [&](size_t bytes) {
    size_t r = o;
    o += (bytes + 255) & ~(size_t)255;
    return r;
  };
  f16* xb     = (f16*)(ws + alloc((size_t)T_TOK * D_IN * 2));
  f16* wgut   = (f16*)(ws + alloc((size_t)E_EXP * 2 * H_HID * D_IN * 2)); // 128MB
  f16* wdt    = (f16*)(ws + alloc((size_t)E_EXP * D_IN * H_HID * 2));     // 64MB
  f16* hbuf   = (f16*)(ws + alloc((size_t)NSLOT_PAD * H_HID * 2));        // 135MB
  int* eidx   = (int*)(ws + alloc((size_t)T_TOK * 4));
  float2* pval= (float2*)(ws + alloc((size_t)T_TOK * 8));
  int* counts = (int*)(ws + alloc(64 * 4));
  int* cursors = counts + 8;
  int* offsets = counts + 16;
  int* perm   = (int*)(ws + alloc((size_t)NSLOT_PAD * 4));
  float* gatew= (float*)(ws + alloc((size_t)NSLOT_PAD * 4));
  int2* slotAB= (int2*)(ws + alloc((size_t)T_TOK * 8));
  f16* ybuf   = wgut;  // wgut dead after ffn1; ybuf needs 34MB <= 128MB

  hipMemsetAsync(counts, 0, 64 * 4, stream);

  convert_x_kernel<<<(T_TOK * D_IN / 4 + 255) / 256, 256, 0, stream>>>(
      x, xb, T_TOK * D_IN / 4);
  transpose_cvt_kernel<1><<<dim3(H_HID / 32, D_IN / 32, E_EXP), 256, 0, stream>>>(
      Wg, wgut, D_IN, H_HID, (size_t)2 * H_HID * D_IN);
  transpose_cvt_kernel<2><<<dim3(H_HID / 32, D_IN / 32, E_EXP), 256, 0, stream>>>(
      Wu, wgut, D_IN, H_HID, (size_t)2 * H_HID * D_IN);
  transpose_cvt_kernel<0><<<dim3(D_IN / 32, H_HID / 32, E_EXP), 256, 0, stream>>>(
      Wd, wdt, H_HID, D_IN, (size_t)D_IN * H_HID);
  router_kernel<<<T_TOK / 4, 256, 0, stream>>>(x, Wr, br, eidx, pval, counts);
  scan_kernel<<<1, 64, 0, stream>>>(counts, offsets);
  scatter_kernel<<<T_TOK / 256, 256, 0, stream>>>(eidx, pval, offsets, cursors,
                                                  perm, gatew, slotAB);
  // FFN1: 256 persistent blocks, one per (e,nt); B-panel stays CU-local.
  ffn_8ph_kernel<0><<<dim3(E_EXP * 32), 512, 0, stream>>>(
      xb, wgut, bg, bu, offsets, perm, nullptr, hbuf);
  // FFN2: 1024 blocks, XCD-pair swizzled (all mt of one (e,nt) per XCD).
  ffn_8ph_kernel<1><<<dim3(1024), 512, 0, stream>>>(
      hbuf, wdt, bd, nullptr, offsets, nullptr, gatew, ybuf);
  combine_kernel<<<T_TOK * D_IN / 8 / 256, 256, 0, stream>>>(ybuf, slotAB, out);
}

// Round 5
// 1030.552 us; speedup vs baseline: 1.0760x; 1.0760x over previous
//
#include <hip/hip_runtime.h>
#include <hip/hip_fp16.h>

// MoE: B=4 S=2048 D=1024 E=8 K=2 H=4096. T=8192 tokens, 16384 assignments.
// R5: R3 grid for FFN1 (proven best), nontemporal epilogue stores (stop L3
// write-allocate thrash of resident weights), Wd transpose moved between
// FFN1 and FFN2 (keeps wdt out of L3 during FFN1). Schedule unchanged.

#define T_TOK 8192
#define D_IN  1024
#define E_EXP 8
#define H_HID 4096
#define NSLOT (T_TOK * 2)
#define NSLOT_PAD (NSLOT + 256)

typedef _Float16 f16;
typedef __attribute__((ext_vector_type(8))) _Float16 f16x8;
typedef __attribute__((ext_vector_type(4))) _Float16 f16x4;
typedef __attribute__((ext_vector_type(4))) float f32x4;

__device__ __forceinline__ void gload_lds16(const void* g, void* l) {
  __builtin_amdgcn_global_load_lds(
      (const __attribute__((address_space(1))) unsigned int*)g,
      (__attribute__((address_space(3))) unsigned int*)l, 16, 0, 0);
}

// ---------------- conversion kernels ----------------

__global__ __launch_bounds__(256) void convert_x_kernel(
    const float* __restrict__ x, f16* __restrict__ xb, int n4) {
  int i = blockIdx.x * 256 + threadIdx.x;
  if (i >= n4) return;
  float4 v = ((const float4*)x)[i];
  f16x4 o = {(f16)v.x, (f16)v.y, (f16)v.z, (f16)v.w};
  *(f16x4*)(xb + (size_t)i * 4) = o;
}

// src [e][R][C] f32 -> dst f16 [e][*][R]; MAP0: row=c; MAP1: gate interleave;
// MAP2: up interleave (rows 32j+16.. for source col 16j..).
template<int MAP>
__global__ __launch_bounds__(256) void transpose_cvt_kernel(
    const float* __restrict__ src, f16* __restrict__ dst, int R, int C,
    size_t dstride) {
  __shared__ float tile[32][33];
  int b = blockIdx.z;
  const float* s = src + (size_t)b * R * C;
  f16* d = dst + (size_t)b * dstride;
  int c0 = blockIdx.x * 32, r0 = blockIdx.y * 32;
  int tr = threadIdx.x >> 3;
  int tc4 = (threadIdx.x & 7) * 4;
  float4 v = *(const float4*)(s + (size_t)(r0 + tr) * C + c0 + tc4);
  tile[tr][tc4 + 0] = v.x;
  tile[tr][tc4 + 1] = v.y;
  tile[tr][tc4 + 2] = v.z;
  tile[tr][tc4 + 3] = v.w;
  __syncthreads();
  int c = c0 + tr;
  int ro = (MAP == 0) ? c : (((c >> 4) << 5) + ((MAP == 2) ? 16 : 0) + (c & 15));
  f16x4 o = {(f16)tile[tc4 + 0][tr], (f16)tile[tc4 + 1][tr],
             (f16)tile[tc4 + 2][tr], (f16)tile[tc4 + 3][tr]};
  *(f16x4*)(d + (size_t)ro * R + r0 + tc4) = o;
}

// ---------------- router ----------------

__global__ __launch_bounds__(256) void router_kernel(
    const float* __restrict__ x, const float* __restrict__ Wr,
    const float* __restrict__ br, int* __restrict__ eidx,
    float2* __restrict__ pval, int* __restrict__ counts) {
  int lane = threadIdx.x & 63, wid = threadIdx.x >> 6;
  int t = blockIdx.x * 4 + wid;
  const float* xr = x + (size_t)t * D_IN;
  float s[8] = {0.f, 0.f, 0.f, 0.f, 0.f, 0.f, 0.f, 0.f};
  int dbase = lane * 16;
#pragma unroll
  for (int i = 0; i < 4; ++i) {
    float4 xv = *(const float4*)(xr + dbase + i * 4);
    const float xs[4] = {xv.x, xv.y, xv.z, xv.w};
#pragma unroll
    for (int j = 0; j < 4; ++j) {
      const float* wr = Wr + (size_t)(dbase + i * 4 + j) * E_EXP;
      float4 w0 = *(const float4*)wr;
      float4 w1 = *(const float4*)(wr + 4);
      float xvj = xs[j];
      s[0] += xvj * w0.x; s[1] += xvj * w0.y; s[2] += xvj * w0.z; s[3] += xvj * w0.w;
      s[4] += xvj * w1.x; s[5] += xvj * w1.y; s[6] += xvj * w1.z; s[7] += xvj * w1.w;
    }
  }
#pragma unroll
  for (int off = 32; off; off >>= 1)
#pragma unroll
    for (int e = 0; e < 8; ++e) s[e] += __shfl_xor(s[e], off);
  if (lane == 0) {
    float v[8];
#pragma unroll
    for (int e = 0; e < 8; ++e) v[e] = s[e] + br[e];
    int i0 = 0; float v0 = v[0];
#pragma unroll
    for (int e = 1; e < 8; ++e) if (v[e] > v0) { v0 = v[e]; i0 = e; }
    int i1 = -1; float v1 = -1e30f;
#pragma unroll
    for (int e = 0; e < 8; ++e)
      if (e != i0 && v[e] > v1) { v1 = v[e]; i1 = e; }
    float ed = __expf(v1 - v0);
    float inv = 1.f / (1.f + ed);
    eidx[t] = i0 | (i1 << 8);
    pval[t] = make_float2(inv, ed * inv);
    atomicAdd(&counts[i0], 1);
    atomicAdd(&counts[i1], 1);
  }
}

__global__ void scan_kernel(const int* __restrict__ counts, int* __restrict__ offsets) {
  if (threadIdx.x == 0) {
    int acc = 0;
#pragma unroll
    for (int e = 0; e < E_EXP; ++e) { offsets[e] = acc; acc += counts[e]; }
    offsets[E_EXP] = acc;
  }
}

__global__ __launch_bounds__(256) void scatter_kernel(
    const int* __restrict__ eidx, const float2* __restrict__ pval,
    const int* __restrict__ offsets, int* __restrict__ cursors,
    int* __restrict__ perm, float* __restrict__ gatew, int2* __restrict__ slotAB) {
  int t = blockIdx.x * 256 + threadIdx.x;
  if (t >= T_TOK) return;
  int ei = eidx[t];
  float2 p = pval[t];
  int e0 = ei & 0xff, e1 = (ei >> 8) & 0xff;
  int s0 = offsets[e0] + atomicAdd(&cursors[e0], 1);
  perm[s0] = t; gatew[s0] = p.x;
  int s1 = offsets[e1] + atomicAdd(&cursors[e1], 1);
  perm[s1] = t; gatew[s1] = p.y;
  slotAB[t] = make_int2(s0, s1);
}

// ---------------- 8-phase 256x256 grouped GEMM ----------------
// 512 thr = 8 waves (2M x 4N). LDS 128KB: buf{0,1} x (A[256][64] | B[256][64]),
// rows 128B, 16B chunk c of row r at physical c^(r&7).
// MODE0 (FFN1): grid (nt, e, mt). A=xb via perm, B=wgut (gate/up 16-col
//   interleave), K=1024, epilogue silu(g)*u -> hbuf (nontemporal).
// MODE1 (FFN2): grid 1024 linear, XCD-pair swizzle. A=hbuf, B=wdt, K=4096,
//   epilogue gate*(acc+bd) -> ybuf.

#define SB0 __builtin_amdgcn_sched_barrier(0)
#define BAR do { SB0; __builtin_amdgcn_s_barrier(); SB0; } while (0)

#define STAGE_(B, ISB, H, KT, BASE) do {                                   \
  char* d_ = smem + (B)*65536 + (ISB)*32768 + (H)*16384 + wid*1024;        \
  gload_lds16(BASE[(H)*2+0] + (size_t)(KT)*64, d_);                        \
  gload_lds16(BASE[(H)*2+1] + (size_t)(KT)*64, d_ + 8192);                 \
} while (0)

#define LDA_(B, Q)                                                          \
  _Pragma("unroll")                                                         \
  for (int m_ = 0; m_ < 4; ++m_) {                                          \
    fa[m_][0] = *(const f16x8*)(smem + (B)*65536 + aoff + ((Q)*4+m_)*2048 + offk0); \
    fa[m_][1] = *(const f16x8*)(smem + (B)*65536 + aoff + ((Q)*4+m_)*2048 + offk1); \
  }

#define LDB_(FB, B, RH)                                                     \
  _Pragma("unroll")                                                         \
  for (int n_ = 0; n_ < 2; ++n_) {                                          \
    FB[n_][0] = *(const f16x8*)(smem + (B)*65536 + 32768 + boff + ((RH)*2+n_)*2048 + offk0); \
    FB[n_][1] = *(const f16x8*)(smem + (B)*65536 + 32768 + boff + ((RH)*2+n_)*2048 + offk1); \
  }

#define QUAD_(Q, RH, FB)                                                    \
  __builtin_amdgcn_s_setprio(1);                                            \
  _Pragma("unroll")                                                         \
  for (int m_ = 0; m_ < 4; ++m_)                                            \
    _Pragma("unroll")                                                       \
    for (int n_ = 0; n_ < 2; ++n_) {                                        \
      acc[(Q)*4+m_][(RH)*2+n_] = __builtin_amdgcn_mfma_f32_16x16x32_f16(    \
          fa[m_][0], FB[n_][0], acc[(Q)*4+m_][(RH)*2+n_], 0, 0, 0);         \
      acc[(Q)*4+m_][(RH)*2+n_] = __builtin_amdgcn_mfma_f32_16x16x32_f16(    \
          fa[m_][1], FB[n_][1], acc[(Q)*4+m_][(RH)*2+n_], 0, 0, 0);         \
    }                                                                       \
  __builtin_amdgcn_s_setprio(0);

template<int MODE>
__global__ __launch_bounds__(512, 2) void ffn_8ph_kernel(
    const f16* __restrict__ Asrc, const f16* __restrict__ Bsrc,
    const float* __restrict__ bias0, const float* __restrict__ bias1,
    const int* __restrict__ offsets, const int* __restrict__ perm,
    const float* __restrict__ gatew, f16* __restrict__ dst) {
  constexpr int KD = MODE ? H_HID : D_IN;        // K dim
  constexpr int BROWS = MODE ? D_IN : 2 * H_HID; // B rows per expert
  constexpr int NT = KD / 64;                    // K-tiles (even)
  static_assert(NT % 2 == 0, "NT even");

  __shared__ __align__(16) char smem[131072];

  int e, nt, mt;
  if constexpr (MODE == 0) {
    nt = blockIdx.x; e = blockIdx.y; mt = blockIdx.z;
  } else {
    int g = blockIdx.x;
    int xcd = g & 7, r = g >> 3;
    int pair = xcd + 8 * (r & 3);   // all mt of one (e,nt) land on one XCD
    e = pair >> 2; nt = pair & 3; mt = r >> 2;
  }
  int off = offsets[e];
  int cnt = offsets[e + 1] - off;
  if (mt * 256 >= cnt) return;

  int tid = threadIdx.x, lane = tid & 63, wid = tid >> 6;
  int wm = wid >> 2, wn = wid & 3;
  int l15 = lane & 15, lc0 = lane >> 4, s7 = l15 & 7;
  int aoff = (wm * 128 + l15) * 128;
  int boff = (wn * 64 + l15) * 128;
  int offk0 = ((lc0) ^ s7) * 16;
  int offk1 = ((lc0 + 4) ^ s7) * 16;

  // chunk geometry shared by A/B staging pointers
  int rowh_[2], lc_[2];
#pragma unroll
  for (int i = 0; i < 2; ++i) {
    int chunk = (i * 8 + wid) * 64 + lane;
    rowh_[i] = chunk >> 3;
    lc_[i] = (chunk & 7) ^ (rowh_[i] & 7);
  }

  const f16 *aB[4], *bB[4];
#pragma unroll
  for (int h = 0; h < 2; ++h)
#pragma unroll
    for (int i = 0; i < 2; ++i) {
      int absrow = h * 128 + rowh_[i];
      bB[h * 2 + i] =
          Bsrc + ((size_t)e * BROWS + nt * 256 + absrow) * KD + lc_[i] * 8;
      int slot = off + min(mt * 256 + absrow, cnt - 1);
      if constexpr (MODE == 0)
        aB[h * 2 + i] = Asrc + (size_t)perm[slot] * KD + lc_[i] * 8;
      else
        aB[h * 2 + i] = Asrc + (size_t)slot * KD + lc_[i] * 8;
    }

  // hoisted biases
  float bv0[4], bv1[2];
  if constexpr (MODE == 0) {
#pragma unroll
    for (int p = 0; p < 2; ++p) {
      int h = nt * 128 + wn * 32 + p * 16 + l15;
      bv0[p] = bias0[e * H_HID + h];
      bv1[p] = bias1[e * H_HID + h];
    }
  } else {
#pragma unroll
    for (int n = 0; n < 4; ++n)
      bv0[n] = bias0[e * D_IN + nt * 256 + wn * 64 + n * 16 + l15];
  }

  f32x4 acc[8][4] = {};
  f16x8 fa[4][2], fb01[2][2], fb23[2][2];

  // prologue: buf0 <- tile0 (B,A), buf1.B <- tile1
  STAGE_(0, 1, 0, 0, bB); STAGE_(0, 1, 1, 0, bB);
  STAGE_(0, 0, 0, 0, aB); STAGE_(0, 0, 1, 0, aB);
  STAGE_(1, 1, 0, 1, bB); STAGE_(1, 1, 1, 1, bB);
  asm volatile("s_waitcnt vmcnt(4)" ::: "memory");
  BAR;

  for (int it = 0; it < NT / 2; ++it) {
    int t1 = 2 * it + 1;
    int t2 = min(2 * it + 2, NT - 1);
    int t3 = min(2 * it + 3, NT - 1);
    // P1: compute t0.quad(0,0) from buf0; stage buf1.A0 (t1)
    LDA_(0, 0); LDB_(fb01, 0, 0); STAGE_(1, 0, 0, t1, aB);
    BAR; QUAD_(0, 0, fb01); BAR;
    // P2
    LDB_(fb23, 0, 1); STAGE_(1, 0, 1, t1, aB);
    BAR; QUAD_(0, 1, fb23); BAR;
    // P3
    LDA_(0, 1); STAGE_(0, 1, 0, t2, bB);
    BAR; QUAD_(1, 0, fb01); BAR;
    // P4
    STAGE_(0, 1, 1, t2, bB);
    asm volatile("s_waitcnt vmcnt(4)" ::: "memory");
    BAR; QUAD_(1, 1, fb23); BAR;
    // P5: compute t1 from buf1; stage buf0.A0 (t2)
    LDA_(1, 0); LDB_(fb01, 1, 0); STAGE_(0, 0, 0, t2, aB);
    BAR; QUAD_(0, 0, fb01); BAR;
    // P6
    LDB_(fb23, 1, 1); STAGE_(0, 0, 1, t2, aB);
    BAR; QUAD_(0, 1, fb23); BAR;
    // P7
    LDA_(1, 1); STAGE_(1, 1, 0, t3, bB);
    BAR; QUAD_(1, 0, fb01); BAR;
    // P8
    STAGE_(1, 1, 1, t3, bB);
    asm volatile("s_waitcnt vmcnt(4)" ::: "memory");
    BAR; QUAD_(1, 1, fb23); BAR;
  }

  asm volatile("s_waitcnt vmcnt(0)" ::: "memory");
  BAR;

  int c0_ = lc0 * 4;
  if constexpr (MODE == 0) {
#pragma unroll
    for (int p = 0; p < 2; ++p) {
      int h = nt * 128 + wn * 32 + p * 16 + l15;
#pragma unroll
      for (int m = 0; m < 8; ++m) {
        int lbase = mt * 256 + wm * 128 + m * 16 + c0_;
#pragma unroll
        for (int r = 0; r < 4; ++r) {
          if (lbase + r < cnt) {
            float gv = acc[m][2 * p][r] + bv0[p];
            float uv = acc[m][2 * p + 1][r] + bv1[p];
            __builtin_nontemporal_store(
                (f16)((gv / (1.f + __expf(-gv))) * uv),
                &dst[(size_t)(off + lbase + r) * H_HID + h]);
          }
        }
      }
    }
  } else {
#pragma unroll
    for (int n = 0; n < 4; ++n) {
      int col = nt * 256 + wn * 64 + n * 16 + l15;
#pragma unroll
      for (int m = 0; m < 8; ++m) {
        int lbase = mt * 256 + wm * 128 + m * 16 + c0_;
#pragma unroll
        for (int r = 0; r < 4; ++r) {
          if (lbase + r < cnt) {
            int slot = off + lbase + r;
            __builtin_nontemporal_store(
                (f16)(gatew[slot] * (acc[m][n][r] + bv0[n])),
                &dst[(size_t)slot * D_IN + col]);
          }
        }
      }
    }
  }
}

// ---------------- combine: out[t] = ybuf[s0] + ybuf[s1] ----------------
__global__ __launch_bounds__(256) void combine_kernel(
    const f16* __restrict__ ybuf, const int2* __restrict__ slotAB,
    float* __restrict__ out) {
  int i = blockIdx.x * 256 + threadIdx.x;
  int t = i >> 7;
  int c8 = i & 127;
  int2 s = slotAB[t];
  f16x8 y0 = *(const f16x8*)(ybuf + (size_t)s.x * D_IN + c8 * 8);
  f16x8 y1 = *(const f16x8*)(ybuf + (size_t)s.y * D_IN + c8 * 8);
  float* o = out + (size_t)t * D_IN + c8 * 8;
  f32x4 o0 = {(float)y0[0] + (float)y1[0], (float)y0[1] + (float)y1[1],
              (float)y0[2] + (float)y1[2], (float)y0[3] + (float)y1[3]};
  f32x4 o1 = {(float)y0[4] + (float)y1[4], (float)y0[5] + (float)y1[5],
              (float)y0[6] + (float)y1[6], (float)y0[7] + (float)y1[7]};
  __builtin_nontemporal_store(o0, (f32x4*)o);
  __builtin_nontemporal_store(o1, (f32x4*)(o + 4));
}

// ---------------- launch ----------------

extern "C" void kernel_launch(void* const* d_in, const int* in_sizes, int n_in,
                              void* d_out, int out_size, void* d_ws, size_t ws_size,
                              hipStream_t stream) {
  const float* x  = (const float*)d_in[0];
  const float* Wr = (const float*)d_in[1];
  const float* br = (const float*)d_in[2];
  const float* Wg = (const float*)d_in[3];
  const float* bg = (const float*)d_in[4];
  const float* Wu = (const float*)d_in[5];
  const float* bu = (const float*)d_in[6];
  const float* Wd = (const float*)d_in[7];
  const float* bd = (const float*)d_in[8];
  float* out = (float*)d_out;

  char* ws = (char*)d_ws;
  size_t o = 0;
  auto alloc = [&](size_t bytes) {
    size_t r = o;
    o += (bytes + 255) & ~(size_t)255;
    return r;
  };
  f16* xb     = (f16*)(ws + alloc((size_t)T_TOK * D_IN * 2));
  f16* wgut   = (f16*)(ws + alloc((size_t)E_EXP * 2 * H_HID * D_IN * 2)); // 128MB
  f16* wdt    = (f16*)(ws + alloc((size_t)E_EXP * D_IN * H_HID * 2));     // 64MB
  f16* hbuf   = (f16*)(ws + alloc((size_t)NSLOT_PAD * H_HID * 2));        // 135MB
  int* eidx   = (int*)(ws + alloc((size_t)T_TOK * 4));
  float2* pval= (float2*)(ws + alloc((size_t)T_TOK * 8));
  int* counts = (int*)(ws + alloc(64 * 4));
  int* cursors = counts + 8;
  int* offsets = counts + 16;
  int* perm   = (int*)(ws + alloc((size_t)NSLOT_PAD * 4));
  float* gatew= (float*)(ws + alloc((size_t)NSLOT_PAD * 4));
  int2* slotAB= (int2*)(ws + alloc((size_t)T_TOK * 8));
  f16* ybuf   = wgut;  // wgut dead after ffn1; ybuf needs 34MB <= 128MB

  hipMemsetAsync(counts, 0, 64 * 4, stream);

  convert_x_kernel<<<(T_TOK * D_IN / 4 + 255) / 256, 256, 0, stream>>>(
      x, xb, T_TOK * D_IN / 4);
  router_kernel<<<T_TOK / 4, 256, 0, stream>>>(x, Wr, br, eidx, pval, counts);
  scan_kernel<<<1, 64, 0, stream>>>(counts, offsets);
  scatter_kernel<<<T_TOK / 256, 256, 0, stream>>>(eidx, pval, offsets, cursors,
                                                  perm, gatew, slotAB);
  transpose_cvt_kernel<1><<<dim3(H_HID / 32, D_IN / 32, E_EXP), 256, 0, stream>>>(
      Wg, wgut, D_IN, H_HID, (size_t)2 * H_HID * D_IN);
  transpose_cvt_kernel<2><<<dim3(H_HID / 32, D_IN / 32, E_EXP), 256, 0, stream>>>(
      Wu, wgut, D_IN, H_HID, (size_t)2 * H_HID * D_IN);
  // FFN1: R3 grid (x=nt fast, z=mt slow) — co-resident blocks share mt round.
  ffn_8ph_kernel<0><<<dim3(2 * H_HID / 256, E_EXP, 32), 512, 0, stream>>>(
      xb, wgut, bg, bu, offsets, perm, nullptr, hbuf);
  // Wd transpose AFTER ffn1: keeps wdt (and its write stream) out of L3
  // while wgut must stay resident.
  transpose_cvt_kernel<0><<<dim3(D_IN / 32, H_HID / 32, E_EXP), 256, 0, stream>>>(
      Wd, wdt, H_HID, D_IN, (size_t)D_IN * H_HID);
  // FFN2: 1024 blocks, XCD-pair swizzled (all mt of one (e,nt) per XCD).
  ffn_8ph_kernel<1><<<dim3(1024), 512, 0, stream>>>(
      hbuf, wdt, bd, nullptr, offsets, nullptr, gatew, ybuf);
  combine_kernel<<<T_TOK * D_IN / 8 / 256, 256, 0, stream>>>(ybuf, slotAB, out);
}

// Round 6
// 1012.478 us; speedup vs baseline: 1.0952x; 1.0179x over previous
//
#include <hip/hip_runtime.h>
#include <hip/hip_fp16.h>

// MoE: B=4 S=2048 D=1024 E=8 K=2 H=4096. T=8192 tokens, 16384 assignments.
// R6: XCD-panel-affinity grids — ALL mt-tiles of one (e,nt) B-panel run
// concurrently on ONE XCD, so the panel lives in that XCD's 4MB L2 and is
// fetched from HBM exactly once. (R4 had the inverse: 32 panels/XCD = 16MB
// > L2 -> thrash. R3/R5 relied on L3 retention across mt-rounds -> 5x refetch.)
// 8-phase 256x256/BK=64 schedule unchanged.

#define T_TOK 8192
#define D_IN  1024
#define E_EXP 8
#define H_HID 4096
#define NSLOT (T_TOK * 2)
#define NSLOT_PAD (NSLOT + 256)

typedef _Float16 f16;
typedef __attribute__((ext_vector_type(8))) _Float16 f16x8;
typedef __attribute__((ext_vector_type(4))) _Float16 f16x4;
typedef __attribute__((ext_vector_type(4))) float f32x4;

__device__ __forceinline__ void gload_lds16(const void* g, void* l) {
  __builtin_amdgcn_global_load_lds(
      (const __attribute__((address_space(1))) unsigned int*)g,
      (__attribute__((address_space(3))) unsigned int*)l, 16, 0, 0);
}

// ---------------- conversion kernels ----------------

__global__ __launch_bounds__(256) void convert_x_kernel(
    const float* __restrict__ x, f16* __restrict__ xb, int n4) {
  int i = blockIdx.x * 256 + threadIdx.x;
  if (i >= n4) return;
  float4 v = ((const float4*)x)[i];
  f16x4 o = {(f16)v.x, (f16)v.y, (f16)v.z, (f16)v.w};
  *(f16x4*)(xb + (size_t)i * 4) = o;
}

// src [e][R][C] f32 -> dst f16 [e][*][R]; MAP0: row=c; MAP1: gate interleave;
// MAP2: up interleave (rows 32j+16.. for source col 16j..).
template<int MAP>
__global__ __launch_bounds__(256) void transpose_cvt_kernel(
    const float* __restrict__ src, f16* __restrict__ dst, int R, int C,
    size_t dstride) {
  __shared__ float tile[32][33];
  int b = blockIdx.z;
  const float* s = src + (size_t)b * R * C;
  f16* d = dst + (size_t)b * dstride;
  int c0 = blockIdx.x * 32, r0 = blockIdx.y * 32;
  int tr = threadIdx.x >> 3;
  int tc4 = (threadIdx.x & 7) * 4;
  float4 v = *(const float4*)(s + (size_t)(r0 + tr) * C + c0 + tc4);
  tile[tr][tc4 + 0] = v.x;
  tile[tr][tc4 + 1] = v.y;
  tile[tr][tc4 + 2] = v.z;
  tile[tr][tc4 + 3] = v.w;
  __syncthreads();
  int c = c0 + tr;
  int ro = (MAP == 0) ? c : (((c >> 4) << 5) + ((MAP == 2) ? 16 : 0) + (c & 15));
  f16x4 o = {(f16)tile[tc4 + 0][tr], (f16)tile[tc4 + 1][tr],
             (f16)tile[tc4 + 2][tr], (f16)tile[tc4 + 3][tr]};
  *(f16x4*)(d + (size_t)ro * R + r0 + tc4) = o;
}

// ---------------- router ----------------

__global__ __launch_bounds__(256) void router_kernel(
    const float* __restrict__ x, const float* __restrict__ Wr,
    const float* __restrict__ br, int* __restrict__ eidx,
    float2* __restrict__ pval, int* __restrict__ counts) {
  int lane = threadIdx.x & 63, wid = threadIdx.x >> 6;
  int t = blockIdx.x * 4 + wid;
  const float* xr = x + (size_t)t * D_IN;
  float s[8] = {0.f, 0.f, 0.f, 0.f, 0.f, 0.f, 0.f, 0.f};
  int dbase = lane * 16;
#pragma unroll
  for (int i = 0; i < 4; ++i) {
    float4 xv = *(const float4*)(xr + dbase + i * 4);
    const float xs[4] = {xv.x, xv.y, xv.z, xv.w};
#pragma unroll
    for (int j = 0; j < 4; ++j) {
      const float* wr = Wr + (size_t)(dbase + i * 4 + j) * E_EXP;
      float4 w0 = *(const float4*)wr;
      float4 w1 = *(const float4*)(wr + 4);
      float xvj = xs[j];
      s[0] += xvj * w0.x; s[1] += xvj * w0.y; s[2] += xvj * w0.z; s[3] += xvj * w0.w;
      s[4] += xvj * w1.x; s[5] += xvj * w1.y; s[6] += xvj * w1.z; s[7] += xvj * w1.w;
    }
  }
#pragma unroll
  for (int off = 32; off; off >>= 1)
#pragma unroll
    for (int e = 0; e < 8; ++e) s[e] += __shfl_xor(s[e], off);
  if (lane == 0) {
    float v[8];
#pragma unroll
    for (int e = 0; e < 8; ++e) v[e] = s[e] + br[e];
    int i0 = 0; float v0 = v[0];
#pragma unroll
    for (int e = 1; e < 8; ++e) if (v[e] > v0) { v0 = v[e]; i0 = e; }
    int i1 = -1; float v1 = -1e30f;
#pragma unroll
    for (int e = 0; e < 8; ++e)
      if (e != i0 && v[e] > v1) { v1 = v[e]; i1 = e; }
    float ed = __expf(v1 - v0);
    float inv = 1.f / (1.f + ed);
    eidx[t] = i0 | (i1 << 8);
    pval[t] = make_float2(inv, ed * inv);
    atomicAdd(&counts[i0], 1);
    atomicAdd(&counts[i1], 1);
  }
}

__global__ void scan_kernel(const int* __restrict__ counts, int* __restrict__ offsets) {
  if (threadIdx.x == 0) {
    int acc = 0;
#pragma unroll
    for (int e = 0; e < E_EXP; ++e) { offsets[e] = acc; acc += counts[e]; }
    offsets[E_EXP] = acc;
  }
}

__global__ __launch_bounds__(256) void scatter_kernel(
    const int* __restrict__ eidx, const float2* __restrict__ pval,
    const int* __restrict__ offsets, int* __restrict__ cursors,
    int* __restrict__ perm, float* __restrict__ gatew, int2* __restrict__ slotAB) {
  int t = blockIdx.x * 256 + threadIdx.x;
  if (t >= T_TOK) return;
  int ei = eidx[t];
  float2 p = pval[t];
  int e0 = ei & 0xff, e1 = (ei >> 8) & 0xff;
  int s0 = offsets[e0] + atomicAdd(&cursors[e0], 1);
  perm[s0] = t; gatew[s0] = p.x;
  int s1 = offsets[e1] + atomicAdd(&cursors[e1], 1);
  perm[s1] = t; gatew[s1] = p.y;
  slotAB[t] = make_int2(s0, s1);
}

// ---------------- 8-phase 256x256 grouped GEMM ----------------
// 512 thr = 8 waves (2M x 4N). LDS 128KB: buf{0,1} x (A[256][64] | B[256][64]),
// rows 128B, 16B chunk c of row r at physical c^(r&7).
// Grid decode (both modes): xcd=g&7, mt=(g>>3)&31, panelIdx=g>>8;
//   panel = xcd + 8*panelIdx. All 32 mt-blocks of a panel land on one XCD
//   (blockIdx%8 -> XCD round-robin), so the B-panel is L2-resident there.
// MODE0 (FFN1): panel->(e=p>>5, nt=p&31). A=xb via perm, B=wgut (gate/up
//   16-col interleave), K=1024, epilogue silu(g)*u -> hbuf (nontemporal).
// MODE1 (FFN2): panel->(e=p>>2, nt=p&3). A=hbuf, B=wdt, K=4096,
//   epilogue gate*(acc+bd) -> ybuf (nontemporal).

#define SB0 __builtin_amdgcn_sched_barrier(0)
#define BAR do { SB0; __builtin_amdgcn_s_barrier(); SB0; } while (0)

#define STAGE_(B, ISB, H, KT, BASE) do {                                   \
  char* d_ = smem + (B)*65536 + (ISB)*32768 + (H)*16384 + wid*1024;        \
  gload_lds16(BASE[(H)*2+0] + (size_t)(KT)*64, d_);                        \
  gload_lds16(BASE[(H)*2+1] + (size_t)(KT)*64, d_ + 8192);                 \
} while (0)

#define LDA_(B, Q)                                                          \
  _Pragma("unroll")                                                         \
  for (int m_ = 0; m_ < 4; ++m_) {                                          \
    fa[m_][0] = *(const f16x8*)(smem + (B)*65536 + aoff + ((Q)*4+m_)*2048 + offk0); \
    fa[m_][1] = *(const f16x8*)(smem + (B)*65536 + aoff + ((Q)*4+m_)*2048 + offk1); \
  }

#define LDB_(FB, B, RH)                                                     \
  _Pragma("unroll")                                                         \
  for (int n_ = 0; n_ < 2; ++n_) {                                          \
    FB[n_][0] = *(const f16x8*)(smem + (B)*65536 + 32768 + boff + ((RH)*2+n_)*2048 + offk0); \
    FB[n_][1] = *(const f16x8*)(smem + (B)*65536 + 32768 + boff + ((RH)*2+n_)*2048 + offk1); \
  }

#define QUAD_(Q, RH, FB)                                                    \
  __builtin_amdgcn_s_setprio(1);                                            \
  _Pragma("unroll")                                                         \
  for (int m_ = 0; m_ < 4; ++m_)                                            \
    _Pragma("unroll")                                                       \
    for (int n_ = 0; n_ < 2; ++n_) {                                        \
      acc[(Q)*4+m_][(RH)*2+n_] = __builtin_amdgcn_mfma_f32_16x16x32_f16(    \
          fa[m_][0], FB[n_][0], acc[(Q)*4+m_][(RH)*2+n_], 0, 0, 0);         \
      acc[(Q)*4+m_][(RH)*2+n_] = __builtin_amdgcn_mfma_f32_16x16x32_f16(    \
          fa[m_][1], FB[n_][1], acc[(Q)*4+m_][(RH)*2+n_], 0, 0, 0);         \
    }                                                                       \
  __builtin_amdgcn_s_setprio(0);

template<int MODE>
__global__ __launch_bounds__(512, 2) void ffn_8ph_kernel(
    const f16* __restrict__ Asrc, const f16* __restrict__ Bsrc,
    const float* __restrict__ bias0, const float* __restrict__ bias1,
    const int* __restrict__ offsets, const int* __restrict__ perm,
    const float* __restrict__ gatew, f16* __restrict__ dst) {
  constexpr int KD = MODE ? H_HID : D_IN;        // K dim
  constexpr int BROWS = MODE ? D_IN : 2 * H_HID; // B rows per expert
  constexpr int NT = KD / 64;                    // K-tiles (even)
  static_assert(NT % 2 == 0, "NT even");

  __shared__ __align__(16) char smem[131072];

  // XCD-panel-affinity decode: all mt of one panel on one XCD.
  int g = blockIdx.x;
  int xcd = g & 7;
  int mt = (g >> 3) & 31;
  int panel = xcd + 8 * (g >> 8);
  int e, nt;
  if constexpr (MODE == 0) { e = panel >> 5; nt = panel & 31; }
  else                     { e = panel >> 2; nt = panel & 3; }

  int off = offsets[e];
  int cnt = offsets[e + 1] - off;
  if (mt * 256 >= cnt) return;

  int tid = threadIdx.x, lane = tid & 63, wid = tid >> 6;
  int wm = wid >> 2, wn = wid & 3;
  int l15 = lane & 15, lc0 = lane >> 4, s7 = l15 & 7;
  int aoff = (wm * 128 + l15) * 128;
  int boff = (wn * 64 + l15) * 128;
  int offk0 = ((lc0) ^ s7) * 16;
  int offk1 = ((lc0 + 4) ^ s7) * 16;

  // chunk geometry shared by A/B staging pointers
  int rowh_[2], lc_[2];
#pragma unroll
  for (int i = 0; i < 2; ++i) {
    int chunk = (i * 8 + wid) * 64 + lane;
    rowh_[i] = chunk >> 3;
    lc_[i] = (chunk & 7) ^ (rowh_[i] & 7);
  }

  const f16 *aB[4], *bB[4];
#pragma unroll
  for (int h = 0; h < 2; ++h)
#pragma unroll
    for (int i = 0; i < 2; ++i) {
      int absrow = h * 128 + rowh_[i];
      bB[h * 2 + i] =
          Bsrc + ((size_t)e * BROWS + nt * 256 + absrow) * KD + lc_[i] * 8;
      int slot = off + min(mt * 256 + absrow, cnt - 1);
      if constexpr (MODE == 0)
        aB[h * 2 + i] = Asrc + (size_t)perm[slot] * KD + lc_[i] * 8;
      else
        aB[h * 2 + i] = Asrc + (size_t)slot * KD + lc_[i] * 8;
    }

  // hoisted biases
  float bv0[4], bv1[2];
  if constexpr (MODE == 0) {
#pragma unroll
    for (int p = 0; p < 2; ++p) {
      int h = nt * 128 + wn * 32 + p * 16 + l15;
      bv0[p] = bias0[e * H_HID + h];
      bv1[p] = bias1[e * H_HID + h];
    }
  } else {
#pragma unroll
    for (int n = 0; n < 4; ++n)
      bv0[n] = bias0[e * D_IN + nt * 256 + wn * 64 + n * 16 + l15];
  }

  f32x4 acc[8][4] = {};
  f16x8 fa[4][2], fb01[2][2], fb23[2][2];

  // prologue: buf0 <- tile0 (B,A), buf1.B <- tile1
  STAGE_(0, 1, 0, 0, bB); STAGE_(0, 1, 1, 0, bB);
  STAGE_(0, 0, 0, 0, aB); STAGE_(0, 0, 1, 0, aB);
  STAGE_(1, 1, 0, 1, bB); STAGE_(1, 1, 1, 1, bB);
  asm volatile("s_waitcnt vmcnt(4)" ::: "memory");
  BAR;

  for (int it = 0; it < NT / 2; ++it) {
    int t1 = 2 * it + 1;
    int t2 = min(2 * it + 2, NT - 1);
    int t3 = min(2 * it + 3, NT - 1);
    // P1: compute t0.quad(0,0) from buf0; stage buf1.A0 (t1)
    LDA_(0, 0); LDB_(fb01, 0, 0); STAGE_(1, 0, 0, t1, aB);
    BAR; QUAD_(0, 0, fb01); BAR;
    // P2
    LDB_(fb23, 0, 1); STAGE_(1, 0, 1, t1, aB);
    BAR; QUAD_(0, 1, fb23); BAR;
    // P3
    LDA_(0, 1); STAGE_(0, 1, 0, t2, bB);
    BAR; QUAD_(1, 0, fb01); BAR;
    // P4
    STAGE_(0, 1, 1, t2, bB);
    asm volatile("s_waitcnt vmcnt(4)" ::: "memory");
    BAR; QUAD_(1, 1, fb23); BAR;
    // P5: compute t1 from buf1; stage buf0.A0 (t2)
    LDA_(1, 0); LDB_(fb01, 1, 0); STAGE_(0, 0, 0, t2, aB);
    BAR; QUAD_(0, 0, fb01); BAR;
    // P6
    LDB_(fb23, 1, 1); STAGE_(0, 0, 1, t2, aB);
    BAR; QUAD_(0, 1, fb23); BAR;
    // P7
    LDA_(1, 1); STAGE_(1, 1, 0, t3, bB);
    BAR; QUAD_(1, 0, fb01); BAR;
    // P8
    STAGE_(1, 1, 1, t3, bB);
    asm volatile("s_waitcnt vmcnt(4)" ::: "memory");
    BAR; QUAD_(1, 1, fb23); BAR;
  }

  asm volatile("s_waitcnt vmcnt(0)" ::: "memory");
  BAR;

  int c0_ = lc0 * 4;
  if constexpr (MODE == 0) {
#pragma unroll
    for (int p = 0; p < 2; ++p) {
      int h = nt * 128 + wn * 32 + p * 16 + l15;
#pragma unroll
      for (int m = 0; m < 8; ++m) {
        int lbase = mt * 256 + wm * 128 + m * 16 + c0_;
#pragma unroll
        for (int r = 0; r < 4; ++r) {
          if (lbase + r < cnt) {
            float gv = acc[m][2 * p][r] + bv0[p];
            float uv = acc[m][2 * p + 1][r] + bv1[p];
            __builtin_nontemporal_store(
                (f16)((gv / (1.f + __expf(-gv))) * uv),
                &dst[(size_t)(off + lbase + r) * H_HID + h]);
          }
        }
      }
    }
  } else {
#pragma unroll
    for (int n = 0; n < 4; ++n) {
      int col = nt * 256 + wn * 64 + n * 16 + l15;
#pragma unroll
      for (int m = 0; m < 8; ++m) {
        int lbase = mt * 256 + wm * 128 + m * 16 + c0_;
#pragma unroll
        for (int r = 0; r < 4; ++r) {
          if (lbase + r < cnt) {
            int slot = off + lbase + r;
            __builtin_nontemporal_store(
                (f16)(gatew[slot] * (acc[m][n][r] + bv0[n])),
                &dst[(size_t)slot * D_IN + col]);
          }
        }
      }
    }
  }
}

// ---------------- combine: out[t] = ybuf[s0] + ybuf[s1] ----------------
__global__ __launch_bounds__(256) void combine_kernel(
    const f16* __restrict__ ybuf, const int2* __restrict__ slotAB,
    float* __restrict__ out) {
  int i = blockIdx.x * 256 + threadIdx.x;
  int t = i >> 7;
  int c8 = i & 127;
  int2 s = slotAB[t];
  f16x8 y0 = *(const f16x8*)(ybuf + (size_t)s.x * D_IN + c8 * 8);
  f16x8 y1 = *(const f16x8*)(ybuf + (size_t)s.y * D_IN + c8 * 8);
  float* o = out + (size_t)t * D_IN + c8 * 8;
  f32x4 o0 = {(float)y0[0] + (float)y1[0], (float)y0[1] + (float)y1[1],
              (float)y0[2] + (float)y1[2], (float)y0[3] + (float)y1[3]};
  f32x4 o1 = {(float)y0[4] + (float)y1[4], (float)y0[5] + (float)y1[5],
              (float)y0[6] + (float)y1[6], (float)y0[7] + (float)y1[7]};
  __builtin_nontemporal_store(o0, (f32x4*)o);
  __builtin_nontemporal_store(o1, (f32x4*)(o + 4));
}

// ---------------- launch ----------------

extern "C" void kernel_launch(void* const* d_in, const int* in_sizes, int n_in,
                              void* d_out, int out_size, void* d_ws, size_t ws_size,
                              hipStream_t stream) {
  const float* x  = (const float*)d_in[0];
  const float* Wr = (const float*)d_in[1];
  const float* br = (const float*)d_in[2];
  const float* Wg = (const float*)d_in[3];
  const float* bg = (const float*)d_in[4];
  const float* Wu = (const float*)d_in[5];
  const float* bu = (const float*)d_in[6];
  const float* Wd = (const float*)d_in[7];
  const float* bd = (const float*)d_in[8];
  float* out = (float*)d_out;

  char* ws = (char*)d_ws;
  size_t o = 0;
  auto alloc = [&](size_t bytes) {
    size_t r = o;
    o += (bytes + 255) & ~(size_t)255;
    return r;
  };
  f16* xb     = (f16*)(ws + alloc((size_t)T_TOK * D_IN * 2));
  f16* wgut   = (f16*)(ws + alloc((size_t)E_EXP * 2 * H_HID * D_IN * 2)); // 128MB
  f16* wdt    = (f16*)(ws + alloc((size_t)E_EXP * D_IN * H_HID * 2));     // 64MB
  f16* hbuf   = (f16*)(ws + alloc((size_t)NSLOT_PAD * H_HID * 2));        // 135MB
  int* eidx   = (int*)(ws + alloc((size_t)T_TOK * 4));
  float2* pval= (float2*)(ws + alloc((size_t)T_TOK * 8));
  int* counts = (int*)(ws + alloc(64 * 4));
  int* cursors = counts + 8;
  int* offsets = counts + 16;
  int* perm   = (int*)(ws + alloc((size_t)NSLOT_PAD * 4));
  float* gatew= (float*)(ws + alloc((size_t)NSLOT_PAD * 4));
  int2* slotAB= (int2*)(ws + alloc((size_t)T_TOK * 8));
  f16* ybuf   = wgut;  // wgut dead after ffn1; ybuf needs 34MB <= 128MB

  hipMemsetAsync(counts, 0, 64 * 4, stream);

  convert_x_kernel<<<(T_TOK * D_IN / 4 + 255) / 256, 256, 0, stream>>>(
      x, xb, T_TOK * D_IN / 4);
  router_kernel<<<T_TOK / 4, 256, 0, stream>>>(x, Wr, br, eidx, pval, counts);
  scan_kernel<<<1, 64, 0, stream>>>(counts, offsets);
  scatter_kernel<<<T_TOK / 256, 256, 0, stream>>>(eidx, pval, offsets, cursors,
                                                  perm, gatew, slotAB);
  transpose_cvt_kernel<1><<<dim3(H_HID / 32, D_IN / 32, E_EXP), 256, 0, stream>>>(
      Wg, wgut, D_IN, H_HID, (size_t)2 * H_HID * D_IN);
  transpose_cvt_kernel<2><<<dim3(H_HID / 32, D_IN / 32, E_EXP), 256, 0, stream>>>(
      Wu, wgut, D_IN, H_HID, (size_t)2 * H_HID * D_IN);
  // FFN1: 8192 blocks, XCD-panel affinity (panel = g&7 + 8*(g>>8), mt inner).
  ffn_8ph_kernel<0><<<dim3(8192), 512, 0, stream>>>(
      xb, wgut, bg, bu, offsets, perm, nullptr, hbuf);
  // Wd transpose after ffn1 keeps wdt out of the cache during ffn1.
  transpose_cvt_kernel<0><<<dim3(D_IN / 32, H_HID / 32, E_EXP), 256, 0, stream>>>(
      Wd, wdt, H_HID, D_IN, (size_t)D_IN * H_HID);
  // FFN2: 1024 blocks, same XCD-panel affinity (32 panels x 32 mt).
  ffn_8ph_kernel<1><<<dim3(1024), 512, 0, stream>>>(
      hbuf, wdt, bd, nullptr, offsets, nullptr, gatew, ybuf);
  combine_kernel<<<T_TOK * D_IN / 8 / 256, 256, 0, stream>>>(ybuf, slotAB, out);
}

// Round 8
// 1002.878 us; speedup vs baseline: 1.1056x; 1.0096x over previous
//
#include <hip/hip_runtime.h>
#include <hip/hip_fp16.h>

// MoE: B=4 S=2048 D=1024 E=8 K=2 H=4096. T=8192 tokens, 16384 assignments.
// R8: fixes R7's race. R7 placed vmcnt AFTER the phase's ds_reads -> reads
// executed before staged LDS writes landed (NaN). Correct placement: drain
// BEFORE the barrier that precedes the reads: vmcnt(6)@prologue,
// vmcnt(4)@P4-end, vmcnt(6)@P8-end. R7's deeper stage placement kept:
// A1H1@P1, B0@P3/P4, A0@P5/P6, B1@P7/P8, A1H0@P8.

#define T_TOK 8192
#define D_IN  1024
#define E_EXP 8
#define H_HID 4096
#define NSLOT (T_TOK * 2)
#define NSLOT_PAD (NSLOT + 256)

typedef _Float16 f16;
typedef __attribute__((ext_vector_type(8))) _Float16 f16x8;
typedef __attribute__((ext_vector_type(4))) _Float16 f16x4;
typedef __attribute__((ext_vector_type(4))) float f32x4;

__device__ __forceinline__ void gload_lds16(const void* g, void* l) {
  __builtin_amdgcn_global_load_lds(
      (const __attribute__((address_space(1))) unsigned int*)g,
      (__attribute__((address_space(3))) unsigned int*)l, 16, 0, 0);
}

// ---------------- weight transpose ----------------
// src [e][R][C] f32 -> dst f16 [e][*][R]; MAP0: row=c; MAP1: gate interleave;
// MAP2: up interleave (rows 32j+16.. for source col 16j..).
template<int MAP>
__global__ __launch_bounds__(256) void transpose_cvt_kernel(
    const float* __restrict__ src, f16* __restrict__ dst, int R, int C,
    size_t dstride) {
  __shared__ float tile[32][33];
  int b = blockIdx.z;
  const float* s = src + (size_t)b * R * C;
  f16* d = dst + (size_t)b * dstride;
  int c0 = blockIdx.x * 32, r0 = blockIdx.y * 32;
  int tr = threadIdx.x >> 3;
  int tc4 = (threadIdx.x & 7) * 4;
  float4 v = *(const float4*)(s + (size_t)(r0 + tr) * C + c0 + tc4);
  tile[tr][tc4 + 0] = v.x;
  tile[tr][tc4 + 1] = v.y;
  tile[tr][tc4 + 2] = v.z;
  tile[tr][tc4 + 3] = v.w;
  __syncthreads();
  int c = c0 + tr;
  int ro = (MAP == 0) ? c : (((c >> 4) << 5) + ((MAP == 2) ? 16 : 0) + (c & 15));
  f16x4 o = {(f16)tile[tc4 + 0][tr], (f16)tile[tc4 + 1][tr],
             (f16)tile[tc4 + 2][tr], (f16)tile[tc4 + 3][tr]};
  *(f16x4*)(d + (size_t)ro * R + r0 + tc4) = o;
}

// ---------------- router (+ x -> f16 conversion fused) ----------------

__global__ __launch_bounds__(256) void router_kernel(
    const float* __restrict__ x, const float* __restrict__ Wr,
    const float* __restrict__ br, int* __restrict__ eidx,
    float2* __restrict__ pval, int* __restrict__ counts,
    f16* __restrict__ xb) {
  int lane = threadIdx.x & 63, wid = threadIdx.x >> 6;
  int t = blockIdx.x * 4 + wid;
  const float* xr = x + (size_t)t * D_IN;
  float s[8] = {0.f, 0.f, 0.f, 0.f, 0.f, 0.f, 0.f, 0.f};
  int dbase = lane * 16;
#pragma unroll
  for (int i = 0; i < 4; ++i) {
    float4 xv = *(const float4*)(xr + dbase + i * 4);
    f16x4 xo = {(f16)xv.x, (f16)xv.y, (f16)xv.z, (f16)xv.w};
    *(f16x4*)(xb + (size_t)t * D_IN + dbase + i * 4) = xo;
    const float xs[4] = {xv.x, xv.y, xv.z, xv.w};
#pragma unroll
    for (int j = 0; j < 4; ++j) {
      const float* wr = Wr + (size_t)(dbase + i * 4 + j) * E_EXP;
      float4 w0 = *(const float4*)wr;
      float4 w1 = *(const float4*)(wr + 4);
      float xvj = xs[j];
      s[0] += xvj * w0.x; s[1] += xvj * w0.y; s[2] += xvj * w0.z; s[3] += xvj * w0.w;
      s[4] += xvj * w1.x; s[5] += xvj * w1.y; s[6] += xvj * w1.z; s[7] += xvj * w1.w;
    }
  }
#pragma unroll
  for (int off = 32; off; off >>= 1)
#pragma unroll
    for (int e = 0; e < 8; ++e) s[e] += __shfl_xor(s[e], off);
  if (lane == 0) {
    float v[8];
#pragma unroll
    for (int e = 0; e < 8; ++e) v[e] = s[e] + br[e];
    int i0 = 0; float v0 = v[0];
#pragma unroll
    for (int e = 1; e < 8; ++e) if (v[e] > v0) { v0 = v[e]; i0 = e; }
    int i1 = -1; float v1 = -1e30f;
#pragma unroll
    for (int e = 0; e < 8; ++e)
      if (e != i0 && v[e] > v1) { v1 = v[e]; i1 = e; }
    float ed = __expf(v1 - v0);
    float inv = 1.f / (1.f + ed);
    eidx[t] = i0 | (i1 << 8);
    pval[t] = make_float2(inv, ed * inv);
    atomicAdd(&counts[i0], 1);
    atomicAdd(&counts[i1], 1);
  }
}

__global__ void scan_kernel(const int* __restrict__ counts, int* __restrict__ offsets) {
  if (threadIdx.x == 0) {
    int acc = 0;
#pragma unroll
    for (int e = 0; e < E_EXP; ++e) { offsets[e] = acc; acc += counts[e]; }
    offsets[E_EXP] = acc;
  }
}

__global__ __launch_bounds__(256) void scatter_kernel(
    const int* __restrict__ eidx, const float2* __restrict__ pval,
    const int* __restrict__ offsets, int* __restrict__ cursors,
    int* __restrict__ perm, float* __restrict__ gatew, int2* __restrict__ slotAB) {
  int t = blockIdx.x * 256 + threadIdx.x;
  if (t >= T_TOK) return;
  int ei = eidx[t];
  float2 p = pval[t];
  int e0 = ei & 0xff, e1 = (ei >> 8) & 0xff;
  int s0 = offsets[e0] + atomicAdd(&cursors[e0], 1);
  perm[s0] = t; gatew[s0] = p.x;
  int s1 = offsets[e1] + atomicAdd(&cursors[e1], 1);
  perm[s1] = t; gatew[s1] = p.y;
  slotAB[t] = make_int2(s0, s1);
}

// ---------------- 8-phase 256x256 grouped GEMM ----------------
// 512 thr = 8 waves (2M x 4N). LDS 128KB: buf{0,1} x (A[256][64] | B[256][64]),
// rows 128B, 16B chunk c of row r at physical c^(r&7).
// Stage schedule (R8): P1: A1H1(odd tile); P3/P4: B0(+2); P5/P6: A0(+2);
// P7/P8: B1(+2); P8: A1H0(+2).
// Waits (drain-before-barrier): vmcnt(6) prologue; vmcnt(4) end-P4 (buf1
// ready for P5 reads); vmcnt(6) end-P8 (buf0 ready for next P1 reads).

#define SB0 __builtin_amdgcn_sched_barrier(0)
#define BAR do { SB0; __builtin_amdgcn_s_barrier(); SB0; } while (0)
#define VMCNT(N) asm volatile("s_waitcnt vmcnt(" #N ")" ::: "memory")

#define STAGE_(B, ISB, H, KT, BASE) do {                                   \
  char* d_ = smem + (B)*65536 + (ISB)*32768 + (H)*16384 + wid*1024;        \
  gload_lds16(BASE[(H)*2+0] + (size_t)(KT)*64, d_);                        \
  gload_lds16(BASE[(H)*2+1] + (size_t)(KT)*64, d_ + 8192);                 \
} while (0)

#define LDA_(B, Q)                                                          \
  _Pragma("unroll")                                                         \
  for (int m_ = 0; m_ < 4; ++m_) {                                          \
    fa[m_][0] = *(const f16x8*)(smem + (B)*65536 + aoff + ((Q)*4+m_)*2048 + offk0); \
    fa[m_][1] = *(const f16x8*)(smem + (B)*65536 + aoff + ((Q)*4+m_)*2048 + offk1); \
  }

#define LDB_(FB, B, RH)                                                     \
  _Pragma("unroll")                                                         \
  for (int n_ = 0; n_ < 2; ++n_) {                                          \
    FB[n_][0] = *(const f16x8*)(smem + (B)*65536 + 32768 + boff + ((RH)*2+n_)*2048 + offk0); \
    FB[n_][1] = *(const f16x8*)(smem + (B)*65536 + 32768 + boff + ((RH)*2+n_)*2048 + offk1); \
  }

#define QUAD_(Q, RH, FB)                                                    \
  __builtin_amdgcn_s_setprio(1);                                            \
  _Pragma("unroll")                                                         \
  for (int m_ = 0; m_ < 4; ++m_)                                            \
    _Pragma("unroll")                                                       \
    for (int n_ = 0; n_ < 2; ++n_) {                                        \
      acc[(Q)*4+m_][(RH)*2+n_] = __builtin_amdgcn_mfma_f32_16x16x32_f16(    \
          fa[m_][0], FB[n_][0], acc[(Q)*4+m_][(RH)*2+n_], 0, 0, 0);         \
      acc[(Q)*4+m_][(RH)*2+n_] = __builtin_amdgcn_mfma_f32_16x16x32_f16(    \
          fa[m_][1], FB[n_][1], acc[(Q)*4+m_][(RH)*2+n_], 0, 0, 0);         \
    }                                                                       \
  __builtin_amdgcn_s_setprio(0);

template<int MODE>
__global__ __launch_bounds__(512, 2) void ffn_8ph_kernel(
    const f16* __restrict__ Asrc, const f16* __restrict__ Bsrc,
    const float* __restrict__ bias0, const float* __restrict__ bias1,
    const int* __restrict__ offsets, const int* __restrict__ perm,
    const float* __restrict__ gatew, f16* __restrict__ dst) {
  constexpr int KD = MODE ? H_HID : D_IN;        // K dim
  constexpr int BROWS = MODE ? D_IN : 2 * H_HID; // B rows per expert
  constexpr int NT = KD / 64;                    // K-tiles (even)
  static_assert(NT % 2 == 0, "NT even");

  __shared__ __align__(16) char smem[131072];

  // XCD-panel-affinity decode: all mt of one panel on one XCD (R6).
  int g = blockIdx.x;
  int xcd = g & 7;
  int mt = (g >> 3) & 31;
  int panel = xcd + 8 * (g >> 8);
  int e, nt;
  if constexpr (MODE == 0) { e = panel >> 5; nt = panel & 31; }
  else                     { e = panel >> 2; nt = panel & 3; }

  int off = offsets[e];
  int cnt = offsets[e + 1] - off;
  if (mt * 256 >= cnt) return;

  int tid = threadIdx.x, lane = tid & 63, wid = tid >> 6;
  int wm = wid >> 2, wn = wid & 3;
  int l15 = lane & 15, lc0 = lane >> 4, s7 = l15 & 7;
  int aoff = (wm * 128 + l15) * 128;
  int boff = (wn * 64 + l15) * 128;
  int offk0 = ((lc0) ^ s7) * 16;
  int offk1 = ((lc0 + 4) ^ s7) * 16;

  // chunk geometry shared by A/B staging pointers
  int rowh_[2], lc_[2];
#pragma unroll
  for (int i = 0; i < 2; ++i) {
    int chunk = (i * 8 + wid) * 64 + lane;
    rowh_[i] = chunk >> 3;
    lc_[i] = (chunk & 7) ^ (rowh_[i] & 7);
  }

  const f16 *aB[4], *bB[4];
#pragma unroll
  for (int h = 0; h < 2; ++h)
#pragma unroll
    for (int i = 0; i < 2; ++i) {
      int absrow = h * 128 + rowh_[i];
      bB[h * 2 + i] =
          Bsrc + ((size_t)e * BROWS + nt * 256 + absrow) * KD + lc_[i] * 8;
      int slot = off + min(mt * 256 + absrow, cnt - 1);
      if constexpr (MODE == 0)
        aB[h * 2 + i] = Asrc + (size_t)perm[slot] * KD + lc_[i] * 8;
      else
        aB[h * 2 + i] = Asrc + (size_t)slot * KD + lc_[i] * 8;
    }

  // hoisted biases
  float bv0[4], bv1[2];
  if constexpr (MODE == 0) {
#pragma unroll
    for (int p = 0; p < 2; ++p) {
      int h = nt * 128 + wn * 32 + p * 16 + l15;
      bv0[p] = bias0[e * H_HID + h];
      bv1[p] = bias1[e * H_HID + h];
    }
  } else {
#pragma unroll
    for (int n = 0; n < 4; ++n)
      bv0[n] = bias0[e * D_IN + nt * 256 + wn * 64 + n * 16 + l15];
  }

  f32x4 acc[8][4] = {};
  f16x8 fa[4][2], fb01[2][2], fb23[2][2];

  // prologue: buf0.B, buf0.A (t0); buf1.B (t1); buf1.A-H0 (t1) — 14 loads.
  STAGE_(0, 1, 0, 0, bB); STAGE_(0, 1, 1, 0, bB);
  STAGE_(0, 0, 0, 0, aB); STAGE_(0, 0, 1, 0, aB);
  STAGE_(1, 1, 0, 1, bB); STAGE_(1, 1, 1, 1, bB);
  STAGE_(1, 0, 0, 1, aB);
  VMCNT(6);   // buf0 complete; buf1.B + buf1.A-H0 (6) still in flight
  BAR;

  for (int it = 0; it < NT / 2; ++it) {
    int b_ = 2 * it + 1;
    int a2 = min(2 * it + 2, NT - 1);
    int b2 = min(2 * it + 3, NT - 1);
    // P1: read buf0 (ready); finish buf1.A (H1, odd tile)
    LDA_(0, 0); LDB_(fb01, 0, 0); STAGE_(1, 0, 1, b_, aB);
    BAR; QUAD_(0, 0, fb01); BAR;
    // P2
    LDB_(fb23, 0, 1);
    BAR; QUAD_(0, 1, fb23); BAR;
    // P3: buf0.B free (last read P2) -> stage B(a+2)
    LDA_(0, 1); STAGE_(0, 1, 0, a2, bB);
    BAR; QUAD_(1, 0, fb01); BAR;
    // P4: drain so buf1 (prev P7/P8 + this P1) is ready for P5 reads
    STAGE_(0, 1, 1, a2, bB);
    BAR; QUAD_(1, 1, fb23);
    VMCNT(4);   // leaves P3+P4 (buf0.B) in flight
    BAR;
    // P5: read buf1 (ready); buf0.A free (last read P3) -> stage A(a+2)
    LDA_(1, 0); LDB_(fb01, 1, 0); STAGE_(0, 0, 0, a2, aB);
    BAR; QUAD_(0, 0, fb01); BAR;
    // P6
    LDB_(fb23, 1, 1); STAGE_(0, 0, 1, a2, aB);
    BAR; QUAD_(0, 1, fb23); BAR;
    // P7: buf1.B free (last read P6) -> stage B(b+2)
    LDA_(1, 1); STAGE_(1, 1, 0, b2, bB);
    BAR; QUAD_(1, 0, fb01); BAR;
    // P8: drain so buf0 (P3..P6) is ready for next P1 reads
    STAGE_(1, 1, 1, b2, bB); STAGE_(1, 0, 0, b2, aB);
    BAR; QUAD_(1, 1, fb23);
    VMCNT(6);   // leaves P7+P8 (buf1.B + buf1.A-H0) in flight
    BAR;
  }

  int c0_ = lc0 * 4;
  if constexpr (MODE == 0) {
#pragma unroll
    for (int p = 0; p < 2; ++p) {
      int h = nt * 128 + wn * 32 + p * 16 + l15;
#pragma unroll
      for (int m = 0; m < 8; ++m) {
        int lbase = mt * 256 + wm * 128 + m * 16 + c0_;
#pragma unroll
        for (int r = 0; r < 4; ++r) {
          if (lbase + r < cnt) {
            float gv = acc[m][2 * p][r] + bv0[p];
            float uv = acc[m][2 * p + 1][r] + bv1[p];
            __builtin_nontemporal_store(
                (f16)((gv / (1.f + __expf(-gv))) * uv),
                &dst[(size_t)(off + lbase + r) * H_HID + h]);
          }
        }
      }
    }
  } else {
#pragma unroll
    for (int n = 0; n < 4; ++n) {
      int col = nt * 256 + wn * 64 + n * 16 + l15;
#pragma unroll
      for (int m = 0; m < 8; ++m) {
        int lbase = mt * 256 + wm * 128 + m * 16 + c0_;
#pragma unroll
        for (int r = 0; r < 4; ++r) {
          if (lbase + r < cnt) {
            int slot = off + lbase + r;
            __builtin_nontemporal_store(
                (f16)(gatew[slot] * (acc[m][n][r] + bv0[n])),
                &dst[(size_t)slot * D_IN + col]);
          }
        }
      }
    }
  }
}

// ---------------- combine: out[t] = ybuf[s0] + ybuf[s1] ----------------
__global__ __launch_bounds__(256) void combine_kernel(
    const f16* __restrict__ ybuf, const int2* __restrict__ slotAB,
    float* __restrict__ out) {
  int i = blockIdx.x * 256 + threadIdx.x;
  int t = i >> 7;
  int c8 = i & 127;
  int2 s = slotAB[t];
  f16x8 y0 = *(const f16x8*)(ybuf + (size_t)s.x * D_IN + c8 * 8);
  f16x8 y1 = *(const f16x8*)(ybuf + (size_t)s.y * D_IN + c8 * 8);
  float* o = out + (size_t)t * D_IN + c8 * 8;
  f32x4 o0 = {(float)y0[0] + (float)y1[0], (float)y0[1] + (float)y1[1],
              (float)y0[2] + (float)y1[2], (float)y0[3] + (float)y1[3]};
  f32x4 o1 = {(float)y0[4] + (float)y1[4], (float)y0[5] + (float)y1[5],
              (float)y0[6] + (float)y1[6], (float)y0[7] + (float)y1[7]};
  __builtin_nontemporal_store(o0, (f32x4*)o);
  __builtin_nontemporal_store(o1, (f32x4*)(o + 4));
}

// ---------------- launch ----------------

extern "C" void kernel_launch(void* const* d_in, const int* in_sizes, int n_in,
                              void* d_out, int out_size, void* d_ws, size_t ws_size,
                              hipStream_t stream) {
  const float* x  = (const float*)d_in[0];
  const float* Wr = (const float*)d_in[1];
  const float* br = (const float*)d_in[2];
  const float* Wg = (const float*)d_in[3];
  const float* bg = (const float*)d_in[4];
  const float* Wu = (const float*)d_in[5];
  const float* bu = (const float*)d_in[6];
  const float* Wd = (const float*)d_in[7];
  const float* bd = (const float*)d_in[8];
  float* out = (float*)d_out;

  char* ws = (char*)d_ws;
  size_t o = 0;
  auto alloc = [&](size_t bytes) {
    size_t r = o;
    o += (bytes + 255) & ~(size_t)255;
    return r;
  };
  f16* xb     = (f16*)(ws + alloc((size_t)T_TOK * D_IN * 2));
  f16* wgut   = (f16*)(ws + alloc((size_t)E_EXP * 2 * H_HID * D_IN * 2)); // 128MB
  f16* wdt    = (f16*)(ws + alloc((size_t)E_EXP * D_IN * H_HID * 2));     // 64MB
  f16* hbuf   = (f16*)(ws + alloc((size_t)NSLOT_PAD * H_HID * 2));        // 135MB
  int* eidx   = (int*)(ws + alloc((size_t)T_TOK * 4));
  float2* pval= (float2*)(ws + alloc((size_t)T_TOK * 8));
  int* counts = (int*)(ws + alloc(64 * 4));
  int* cursors = counts + 8;
  int* offsets = counts + 16;
  int* perm   = (int*)(ws + alloc((size_t)NSLOT_PAD * 4));
  float* gatew= (float*)(ws + alloc((size_t)NSLOT_PAD * 4));
  int2* slotAB= (int2*)(ws + alloc((size_t)T_TOK * 8));
  f16* ybuf   = wgut;  // wgut dead after ffn1; ybuf needs 34MB <= 128MB

  hipMemsetAsync(counts, 0, 64 * 4, stream);

  router_kernel<<<T_TOK / 4, 256, 0, stream>>>(x, Wr, br, eidx, pval, counts, xb);
  scan_kernel<<<1, 64, 0, stream>>>(counts, offsets);
  scatter_kernel<<<T_TOK / 256, 256, 0, stream>>>(eidx, pval, offsets, cursors,
                                                  perm, gatew, slotAB);
  transpose_cvt_kernel<1><<<dim3(H_HID / 32, D_IN / 32, E_EXP), 256, 0, stream>>>(
      Wg, wgut, D_IN, H_HID, (size_t)2 * H_HID * D_IN);
  transpose_cvt_kernel<2><<<dim3(H_HID / 32, D_IN / 32, E_EXP), 256, 0, stream>>>(
      Wu, wgut, D_IN, H_HID, (size_t)2 * H_HID * D_IN);
  // FFN1: 8192 blocks, XCD-panel affinity (panel = g&7 + 8*(g>>8), mt inner).
  ffn_8ph_kernel<0><<<dim3(8192), 512, 0, stream>>>(
      xb, wgut, bg, bu, offsets, perm, nullptr, hbuf);
  // Wd transpose after ffn1 keeps wdt out of the cache during ffn1.
  transpose_cvt_kernel<0><<<dim3(D_IN / 32, H_HID / 32, E_EXP), 256, 0, stream>>>(
      Wd, wdt, H_HID, D_IN, (size_t)D_IN * H_HID);
  // FFN2: 1024 blocks, same XCD-panel affinity (32 panels x 32 mt).
  ffn_8ph_kernel<1><<<dim3(1024), 512, 0, stream>>>(
      hbuf, wdt, bd, nullptr, offsets, nullptr, gatew, ybuf);
  combine_kernel<<<T_TOK * D_IN / 8 / 256, 256, 0, stream>>>(ybuf, slotAB, out);
}